// Round 19
// baseline (284.286 us; speedup 1.0000x reference)
//
#include <hip/hip_runtime.h>

#define T_DIM 4096
#define B_DIM 256
#define NSEG 8
#define SEGLEN 32
#define BSTRIDE ((size_t)T_DIM * 64)   // floats per b-step in states
// N_OBS=64, H=8, N_ACT=18

// fast sigmoid/tanh via v_rcp_f32 (~1 ULP; verified R13)
#define SIGM(X)  __builtin_amdgcn_rcpf(1.f + __expf(-(X)))
#define TANH(X)  fmaf(2.f, __builtin_amdgcn_rcpf(1.f + __expf(-2.f * (X))), -1.f)

// DPP cross-lane on the VALU pipe (no DS): quad_perm xor1 = 0xB1, xor2 = 0x4E.
__device__ __forceinline__ float dpp_xor1(float x) {
    return __int_as_float(__builtin_amdgcn_update_dpp(
        0, __float_as_int(x), 0xB1, 0xF, 0xF, true));
}
__device__ __forceinline__ float dpp_xor2(float x) {
    return __int_as_float(__builtin_amdgcn_update_dpp(
        0, __float_as_int(x), 0x4E, 0xF, 0xF, true));
}

// ws layout: carryH 1 MiB @ 0, carryC 1 MiB @ 1 MiB, fdbuf 128 KiB @ 2 MiB

#define LOAD_WEIGHTS                                                           \
    float w1s[4][8];                                                           \
    _Pragma("unroll") for (int m = 0; m < 4; ++m)                              \
        _Pragma("unroll") for (int k = 0; k < 8; ++k)                          \
            w1s[m][k] = W1[m * 64 + j * 8 + k];                                \
    float b1r0 = b1[0], b1r1 = b1[1], b1r2 = b1[2], b1r3 = b1[3];              \
    float w2s0 = W2[j*4+0], w2s1 = W2[j*4+1], w2s2 = W2[j*4+2], w2s3 = W2[j*4+3]; \
    float b2r = b2[j];                                                         \
    float wI[8], wF[8], wG[8], wO[8], uI[8], uF[8], uG[8], uO[8];              \
    _Pragma("unroll") for (int k = 0; k < 8; ++k) {                            \
        wI[k] = Wih[j * 8 + k];        uI[k] = Whh[j * 8 + k];                 \
        wF[k] = Wih[(8 + j) * 8 + k];  uF[k] = Whh[(8 + j) * 8 + k];           \
        wG[k] = Wih[(16 + j) * 8 + k]; uG[k] = Whh[(16 + j) * 8 + k];          \
        wO[k] = Wih[(24 + j) * 8 + k]; uO[k] = Whh[(24 + j) * 8 + k];          \
    }                                                                          \
    float bI = bih[j] + bhh[j],      bF = bih[8 + j] + bhh[8 + j];             \
    float bG = bih[16 + j] + bhh[16 + j], bO = bih[24 + j] + bhh[24 + j];      \
    float hw0[8], hw1[8], hw2[8];                                              \
    float hb0 = ba[j], hb1 = ba[8 + j], hb2 = 0.f;                             \
    _Pragma("unroll") for (int k = 0; k < 8; ++k) {                            \
        hw0[k] = Wa[j * 8 + k]; hw1[k] = Wa[(8 + j) * 8 + k]; hw2[k] = 0.f;    \
    }                                                                          \
    if (j < 2) {                                                               \
        _Pragma("unroll") for (int k = 0; k < 8; ++k) hw2[k] = Wa[(16+j)*8+k]; \
        hb2 = ba[16 + j];                                                      \
    } else if (j == 2) {                                                       \
        _Pragma("unroll") for (int k = 0; k < 8; ++k) hw2[k] = Wv[k];          \
        hb2 = bv[0];                                                           \
    }

#define CORE_S(DONEE, SA, SV)                                                  \
        float p0 = SA.x * w1s[0][0], p1 = SA.x * w1s[1][0];                    \
        float p2 = SA.x * w1s[2][0], p3 = SA.x * w1s[3][0];                    \
        p0 = fmaf(SA.y, w1s[0][1], p0); p1 = fmaf(SA.y, w1s[1][1], p1);        \
        p2 = fmaf(SA.y, w1s[2][1], p2); p3 = fmaf(SA.y, w1s[3][1], p3);        \
        p0 = fmaf(SA.z, w1s[0][2], p0); p1 = fmaf(SA.z, w1s[1][2], p1);        \
        p2 = fmaf(SA.z, w1s[2][2], p2); p3 = fmaf(SA.z, w1s[3][2], p3);        \
        p0 = fmaf(SA.w, w1s[0][3], p0); p1 = fmaf(SA.w, w1s[1][3], p1);        \
        p2 = fmaf(SA.w, w1s[2][3], p2); p3 = fmaf(SA.w, w1s[3][3], p3);        \
        p0 = fmaf(SV.x, w1s[0][4], p0); p1 = fmaf(SV.x, w1s[1][4], p1);        \
        p2 = fmaf(SV.x, w1s[2][4], p2); p3 = fmaf(SV.x, w1s[3][4], p3);        \
        p0 = fmaf(SV.y, w1s[0][5], p0); p1 = fmaf(SV.y, w1s[1][5], p1);        \
        p2 = fmaf(SV.y, w1s[2][5], p2); p3 = fmaf(SV.y, w1s[3][5], p3);        \
        p0 = fmaf(SV.z, w1s[0][6], p0); p1 = fmaf(SV.z, w1s[1][6], p1);        \
        p2 = fmaf(SV.z, w1s[2][6], p2); p3 = fmaf(SV.z, w1s[3][6], p3);        \
        p0 = fmaf(SV.w, w1s[0][7], p0); p1 = fmaf(SV.w, w1s[1][7], p1);        \
        p2 = fmaf(SV.w, w1s[2][7], p2); p3 = fmaf(SV.w, w1s[3][7], p3);        \
        p0 += dpp_xor1(p0); p1 += dpp_xor1(p1);                                \
        p2 += dpp_xor1(p2); p3 += dpp_xor1(p3);                                \
        p0 += dpp_xor2(p0); p1 += dpp_xor2(p1);                                \
        p2 += dpp_xor2(p2); p3 += dpp_xor2(p3);                                \
        p0 += __shfl_xor(p0, 4, 64); p1 += __shfl_xor(p1, 4, 64);              \
        p2 += __shfl_xor(p2, 4, 64); p3 += __shfl_xor(p3, 4, 64);              \
        float y0 = fmaxf(p0 + b1r0, 0.f);                                      \
        float y1 = fmaxf(p1 + b1r1, 0.f);                                      \
        float y2 = fmaxf(p2 + b1r2, 0.f);                                      \
        float y3 = fmaxf(p3 + b1r3, 0.f);                                      \
        float xj = fmaf(y3, w2s3, fmaf(y2, w2s2, fmaf(y1, w2s1,                \
                   fmaf(y0, w2s0, b2r))));                                     \
        xj = fmaxf(xj, 0.f);                                                   \
        float x0 = __shfl(xj, gb | 0, 64);                                     \
        float x1 = __shfl(xj, gb | 1, 64);                                     \
        float xx2 = __shfl(xj, gb | 2, 64);                                    \
        float x3 = __shfl(xj, gb | 3, 64);                                     \
        float x4 = __shfl(xj, gb | 4, 64);                                     \
        float x5 = __shfl(xj, gb | 5, 64);                                     \
        float x6 = __shfl(xj, gb | 6, 64);                                     \
        float x7 = __shfl(xj, gb | 7, 64);                                     \
        float gi = bI, gf = bF, gg = bG, go = bO;                              \
        gi = fmaf(x0, wI[0], gi); gi = fmaf(x1, wI[1], gi);                    \
        gi = fmaf(xx2, wI[2], gi); gi = fmaf(x3, wI[3], gi);                   \
        gi = fmaf(x4, wI[4], gi); gi = fmaf(x5, wI[5], gi);                    \
        gi = fmaf(x6, wI[6], gi); gi = fmaf(x7, wI[7], gi);                    \
        gf = fmaf(x0, wF[0], gf); gf = fmaf(x1, wF[1], gf);                    \
        gf = fmaf(xx2, wF[2], gf); gf = fmaf(x3, wF[3], gf);                   \
        gf = fmaf(x4, wF[4], gf); gf = fmaf(x5, wF[5], gf);                    \
        gf = fmaf(x6, wF[6], gf); gf = fmaf(x7, wF[7], gf);                    \
        gg = fmaf(x0, wG[0], gg); gg = fmaf(x1, wG[1], gg);                    \
        gg = fmaf(xx2, wG[2], gg); gg = fmaf(x3, wG[3], gg);                   \
        gg = fmaf(x4, wG[4], gg); gg = fmaf(x5, wG[5], gg);                    \
        gg = fmaf(x6, wG[6], gg); gg = fmaf(x7, wG[7], gg);                    \
        go = fmaf(x0, wO[0], go); go = fmaf(x1, wO[1], go);                    \
        go = fmaf(xx2, wO[2], go); go = fmaf(x3, wO[3], go);                   \
        go = fmaf(x4, wO[4], go); go = fmaf(x5, wO[5], go);                    \
        go = fmaf(x6, wO[6], go); go = fmaf(x7, wO[7], go);                    \
        float dI = h[0] * uI[0], dF = h[0] * uF[0];                            \
        float dG = h[0] * uG[0], dO = h[0] * uO[0];                            \
        dI = fmaf(h[1], uI[1], dI); dF = fmaf(h[1], uF[1], dF);                \
        dG = fmaf(h[1], uG[1], dG); dO = fmaf(h[1], uO[1], dO);                \
        dI = fmaf(h[2], uI[2], dI); dF = fmaf(h[2], uF[2], dF);                \
        dG = fmaf(h[2], uG[2], dG); dO = fmaf(h[2], uO[2], dO);                \
        dI = fmaf(h[3], uI[3], dI); dF = fmaf(h[3], uF[3], dF);                \
        dG = fmaf(h[3], uG[3], dG); dO = fmaf(h[3], uO[3], dO);                \
        dI = fmaf(h[4], uI[4], dI); dF = fmaf(h[4], uF[4], dF);                \
        dG = fmaf(h[4], uG[4], dG); dO = fmaf(h[4], uO[4], dO);                \
        dI = fmaf(h[5], uI[5], dI); dF = fmaf(h[5], uF[5], dF);                \
        dG = fmaf(h[5], uG[5], dG); dO = fmaf(h[5], uO[5], dO);                \
        dI = fmaf(h[6], uI[6], dI); dF = fmaf(h[6], uF[6], dF);                \
        dG = fmaf(h[6], uG[6], dG); dO = fmaf(h[6], uO[6], dO);                \
        dI = fmaf(h[7], uI[7], dI); dF = fmaf(h[7], uF[7], dF);                \
        dG = fmaf(h[7], uG[7], dG); dO = fmaf(h[7], uO[7], dO);                \
        float GI = (DONEE) ? gi : (gi + dI);                                   \
        float GF = (DONEE) ? gf : (gf + dF);                                   \
        float GG = (DONEE) ? gg : (gg + dG);                                   \
        float GO = (DONEE) ? go : (go + dO);                                   \
        float cin = (DONEE) ? 0.f : c;                                         \
        float i_ = SIGM(GI);                                                   \
        float f_ = SIGM(GF);                                                   \
        float g_ = TANH(GG);                                                   \
        float o_ = SIGM(GO);                                                   \
        float c2 = fmaf(f_, cin, i_ * g_);                                     \
        float th = TANH(c2);                                                   \
        float h2 = o_ * th;

#define HEADS                                                                  \
        float o0 = hb0, o1 = hb1, o2 = hb2;                                    \
        o0 = fmaf(h[0], hw0[0], o0); o1 = fmaf(h[0], hw1[0], o1);              \
        o2 = fmaf(h[0], hw2[0], o2);                                           \
        o0 = fmaf(h[1], hw0[1], o0); o1 = fmaf(h[1], hw1[1], o1);              \
        o2 = fmaf(h[1], hw2[1], o2);                                           \
        o0 = fmaf(h[2], hw0[2], o0); o1 = fmaf(h[2], hw1[2], o1);              \
        o2 = fmaf(h[2], hw2[2], o2);                                           \
        o0 = fmaf(h[3], hw0[3], o0); o1 = fmaf(h[3], hw1[3], o1);              \
        o2 = fmaf(h[3], hw2[3], o2);                                           \
        o0 = fmaf(h[4], hw0[4], o0); o1 = fmaf(h[4], hw1[4], o1);              \
        o2 = fmaf(h[4], hw2[4], o2);                                           \
        o0 = fmaf(h[5], hw0[5], o0); o1 = fmaf(h[5], hw1[5], o1);              \
        o2 = fmaf(h[5], hw2[5], o2);                                           \
        o0 = fmaf(h[6], hw0[6], o0); o1 = fmaf(h[6], hw1[6], o1);              \
        o2 = fmaf(h[6], hw2[6], o2);                                           \
        o0 = fmaf(h[7], hw0[7], o0); o1 = fmaf(h[7], hw1[7], o1);              \
        o2 = fmaf(h[7], hw2[7], o2);

#define HSHFL                                                                  \
        h[0] = __shfl(h2, gb | 0, 64); h[1] = __shfl(h2, gb | 1, 64);          \
        h[2] = __shfl(h2, gb | 2, 64); h[3] = __shfl(h2, gb | 3, 64);          \
        h[4] = __shfl(h2, gb | 4, 64); h[5] = __shfl(h2, gb | 5, 64);          \
        h[6] = __shfl(h2, gb | 6, 64); h[7] = __shfl(h2, gb | 7, 64);

// ---------------------------------------------------------------------------
// Pass 1 (fused, R18-identical body) with `rep` outer loop (idempotent) for
// rocprof visibility: at rep=3 it exceeds the ~150us harness fills.
// ---------------------------------------------------------------------------
__global__ __launch_bounds__(64) void pass1_kernel(
    const float* __restrict__ states, const int* __restrict__ dones,
    const float* __restrict__ hx,
    const float* __restrict__ W1, const float* __restrict__ b1,
    const float* __restrict__ W2, const float* __restrict__ b2,
    const float* __restrict__ Wih, const float* __restrict__ bih,
    const float* __restrict__ Whh, const float* __restrict__ bhh,
    const float* __restrict__ Wa, const float* __restrict__ ba,
    const float* __restrict__ Wv, const float* __restrict__ bv,
    float* __restrict__ out,
    float* __restrict__ carryH, float* __restrict__ carryC,
    int* __restrict__ fdbuf, int rep)
{
    int lane = threadIdx.x;
    int col  = lane >> 3;
    int j    = lane & 7;
    int gb   = lane & 56;
    int s    = blockIdx.x >> 9;
    int tb   = blockIdx.x & 511;
    int t    = tb * 8 + col;
    int b0   = s * SEGLEN;

    LOAD_WEIGHTS

    for (int r0 = 0; r0 < rep; ++r0) {
        float h[8]; float c;
        if (s == 0) {
#pragma unroll
            for (int m = 0; m < 8; ++m) h[m] = hx[t * 8 + m];
            c = hx[T_DIM * 8 + t * 8 + j];
        } else {
#pragma unroll
            for (int m = 0; m < 8; ++m) h[m] = 0.f;
            c = 0.f;
        }

        const float* sbase = states + ((size_t)b0 * T_DIM + t) * 64 + j * 8;
        const int*   dbase = dones + (size_t)b0 * T_DIM + t;
        float* outA = out + ((size_t)b0 * T_DIM + t) * 18;
        float* outV = out + (size_t)18 * B_DIM * T_DIM + (size_t)b0 * T_DIM + t;
        int fd = SEGLEN;

        int dn0, dn1, dn2, dn3;
        float4 sa0, sv0, sa1, sv1, sa2, sv2, sa3, sv3;
#define PF(I) \
        dn##I = dbase[(size_t)(I) * T_DIM]; \
        sa##I = *(const float4*)(sbase + (size_t)(I) * BSTRIDE); \
        sv##I = *(const float4*)(sbase + (size_t)(I) * BSTRIDE + 4);
        PF(0) PF(1) PF(2) PF(3)
#undef PF

#define P1STEP(KK, DN, SA, SV)                                                 \
        {                                                                      \
            int done = DN; float4 sa = SA, sv = SV;                            \
            int kp = (KK) + 4; kp = (kp > SEGLEN - 1) ? (SEGLEN - 1) : kp;     \
            DN = dbase[(size_t)kp * T_DIM];                                    \
            SA = *(const float4*)(sbase + (size_t)kp * BSTRIDE);               \
            SV = *(const float4*)(sbase + (size_t)kp * BSTRIDE + 4);           \
            CORE_S(done, sa, sv)                                               \
            c = c2;                                                            \
            HSHFL                                                              \
            fd = (done && fd == SEGLEN) ? (KK) : fd;                           \
            HEADS                                                              \
            outA[j] = o0; outA[8 + j] = o1;                                    \
            if (j < 2) outA[16 + j] = o2; else if (j == 2) *outV = o2;         \
            outA += (size_t)T_DIM * 18; outV += T_DIM;                         \
        }

        for (int k0 = 0; k0 < SEGLEN; k0 += 4) {
            P1STEP(k0 + 0, dn0, sa0, sv0);
            P1STEP(k0 + 1, dn1, sa1, sv1);
            P1STEP(k0 + 2, dn2, sa2, sv2);
            P1STEP(k0 + 3, dn3, sa3, sv3);
        }
#undef P1STEP

        carryH[((size_t)s * T_DIM + t) * 8 + j] = h[j];
        carryC[((size_t)s * T_DIM + t) * 8 + j] = c;
        if (j == 0) fdbuf[(size_t)s * T_DIM + t] = fd;
    }
}

// ---------------------------------------------------------------------------
// Pass 2 (fused, parallel; R18-identical).
// ---------------------------------------------------------------------------
__global__ __launch_bounds__(64) void pass2_kernel(
    const float* __restrict__ states, const int* __restrict__ dones,
    const float* __restrict__ W1, const float* __restrict__ b1,
    const float* __restrict__ W2, const float* __restrict__ b2,
    const float* __restrict__ Wih, const float* __restrict__ bih,
    const float* __restrict__ Whh, const float* __restrict__ bhh,
    const float* __restrict__ Wa, const float* __restrict__ ba,
    const float* __restrict__ Wv, const float* __restrict__ bv,
    float* __restrict__ out,
    const float* __restrict__ carryH, const float* __restrict__ carryC,
    const int* __restrict__ fdbuf)
{
    int lane = threadIdx.x;
    int col  = lane >> 3;
    int j    = lane & 7;
    int gb   = lane & 56;
    int s    = 1 + (int)(blockIdx.x >> 9);   // 1..NSEG-1
    int tb   = blockIdx.x & 511;
    int t    = tb * 8 + col;

    LOAD_WEIGHTS

    const float* sb2 = states + (size_t)t * 64 + j * 8;

    float h[8]; float c;
    bool prev_exact = (s == 1) ||
                      (fdbuf[(size_t)(s - 1) * T_DIM + t] < SEGLEN);
    if (__all(prev_exact)) {
#pragma unroll
        for (int m = 0; m < 8; ++m)
            h[m] = carryH[((size_t)(s - 1) * T_DIM + t) * 8 + m];
        c = carryC[((size_t)(s - 1) * T_DIM + t) * 8 + j];
    } else {
#pragma unroll
        for (int m = 0; m < 8; ++m) h[m] = carryH[(size_t)t * 8 + m];
        c = carryC[(size_t)t * 8 + j];
        for (int p = 1; p <= s - 1; ++p) {
            size_t bb = (size_t)p * SEGLEN;
            for (int k = 0; k < SEGLEN; ++k) {
                int done = dones[(bb + k) * T_DIM + t];
                float4 sa = *(const float4*)(sb2 + (bb + k) * BSTRIDE);
                float4 sv = *(const float4*)(sb2 + (bb + k) * BSTRIDE + 4);
                CORE_S(done, sa, sv)
                c = c2;
                HSHFL
            }
            int fdp = fdbuf[(size_t)p * T_DIM + t];
            if (fdp < SEGLEN) {
#pragma unroll
                for (int m = 0; m < 8; ++m)
                    h[m] = carryH[((size_t)p * T_DIM + t) * 8 + m];
                c = carryC[((size_t)p * T_DIM + t) * 8 + j];
            }
        }
    }

    int fd = fdbuf[(size_t)s * T_DIM + t];
    int wmax = fd;
#pragma unroll
    for (int d = 1; d < 64; d <<= 1) {
        int o = __shfl_xor(wmax, d, 64);
        wmax = (o > wmax) ? o : wmax;
    }
    size_t bbase = (size_t)s * SEGLEN;
    float4 csa = *(const float4*)(sb2 + bbase * BSTRIDE);
    float4 csv = *(const float4*)(sb2 + bbase * BSTRIDE + 4);
    for (int k = 0; k < wmax; ++k) {
        bool act = (k < fd);                 // no dones in [0, fd) by def.
        float4 sa = csa, sv = csv;
        int kn = k + 1; kn = (kn > SEGLEN - 1) ? (SEGLEN - 1) : kn;
        csa = *(const float4*)(sb2 + (bbase + kn) * BSTRIDE);
        csv = *(const float4*)(sb2 + (bbase + kn) * BSTRIDE + 4);
        CORE_S(0, sa, sv)
        c = act ? c2 : c;
        float n0 = __shfl(h2, gb | 0, 64), n1 = __shfl(h2, gb | 1, 64);
        float n2 = __shfl(h2, gb | 2, 64), n3 = __shfl(h2, gb | 3, 64);
        float n4 = __shfl(h2, gb | 4, 64), n5 = __shfl(h2, gb | 5, 64);
        float n6 = __shfl(h2, gb | 6, 64), n7 = __shfl(h2, gb | 7, 64);
        h[0] = act ? n0 : h[0]; h[1] = act ? n1 : h[1];
        h[2] = act ? n2 : h[2]; h[3] = act ? n3 : h[3];
        h[4] = act ? n4 : h[4]; h[5] = act ? n5 : h[5];
        h[6] = act ? n6 : h[6]; h[7] = act ? n7 : h[7];
        HEADS
        if (act) {
            float* outA = out + ((bbase + k) * T_DIM + t) * 18;
            outA[j] = o0; outA[8 + j] = o1;
            if (j < 2) outA[16 + j] = o2;
            else if (j == 2)
                out[(size_t)18 * B_DIM * T_DIM + (bbase + k) * T_DIM + t] = o2;
        }
    }
}

// ---------------------------------------------------------------------------
extern "C" void kernel_launch(void* const* d_in, const int* in_sizes, int n_in,
                              void* d_out, int out_size, void* d_ws, size_t ws_size,
                              hipStream_t stream) {
    (void)in_sizes; (void)n_in; (void)out_size; (void)ws_size;
    const float* states = (const float*)d_in[0];
    const int*   dones  = (const int*)d_in[1];
    const float* hx     = (const float*)d_in[2];
    const float* W1     = (const float*)d_in[3];
    const float* b1     = (const float*)d_in[4];
    const float* W2     = (const float*)d_in[5];
    const float* b2     = (const float*)d_in[6];
    const float* Wih    = (const float*)d_in[7];
    const float* bih    = (const float*)d_in[8];
    const float* Whh    = (const float*)d_in[9];
    const float* bhh    = (const float*)d_in[10];
    const float* Wa     = (const float*)d_in[11];
    const float* ba     = (const float*)d_in[12];
    const float* Wv     = (const float*)d_in[13];
    const float* bv     = (const float*)d_in[14];
    float* out = (float*)d_out;

    float* carryH = (float*)d_ws;                               // 1 MiB
    float* carryC = (float*)((char*)d_ws + (1u << 20));         // 1 MiB
    int*   fdbuf  = (int*)((char*)d_ws + (2u << 20));           // 128 KiB

    // MEASUREMENT ROUND: rep=3 surfaces pass1 in rocprof top-5 with its
    // VGPR/Occupancy/VALUBusy/BW counters (body idempotent).
    pass1_kernel<<<NSEG * 512, 64, 0, stream>>>(states, dones, hx, W1, b1, W2, b2,
                                                Wih, bih, Whh, bhh, Wa, ba, Wv, bv,
                                                out, carryH, carryC, fdbuf, 3);
    pass2_kernel<<<(NSEG - 1) * 512, 64, 0, stream>>>(states, dones, W1, b1, W2, b2,
                                                      Wih, bih, Whh, bhh, Wa, ba, Wv, bv,
                                                      out, carryH, carryC, fdbuf);
}

// Round 20
// 93.119 us; speedup vs baseline: 3.0529x; 3.0529x over previous
//
#include <hip/hip_runtime.h>

#define T_DIM 4096
#define B_DIM 256
#define NSEG 8
#define SEGLEN 32
#define BSTRIDE ((size_t)T_DIM * 64)   // floats per b-step in states
// N_OBS=64, H=8, N_ACT=18

// fast sigmoid/tanh via v_rcp_f32 (~1 ULP; verified R13)
#define SIGM(X)  __builtin_amdgcn_rcpf(1.f + __expf(-(X)))
#define TANH(X)  fmaf(2.f, __builtin_amdgcn_rcpf(1.f + __expf(-2.f * (X))), -1.f)

// DPP cross-lane on the VALU pipe (no DS): quad_perm xor1 = 0xB1, xor2 = 0x4E.
__device__ __forceinline__ float dpp_xor1(float x) {
    return __int_as_float(__builtin_amdgcn_update_dpp(
        0, __float_as_int(x), 0xB1, 0xF, 0xF, true));
}
__device__ __forceinline__ float dpp_xor2(float x) {
    return __int_as_float(__builtin_amdgcn_update_dpp(
        0, __float_as_int(x), 0x4E, 0xF, 0xF, true));
}

// ws layout: carryH 1 MiB @ 0, carryC 1 MiB @ 1 MiB, fdbuf 128 KiB @ 2 MiB

#define LOAD_WEIGHTS                                                           \
    float w1s[4][8];                                                           \
    _Pragma("unroll") for (int m = 0; m < 4; ++m)                              \
        _Pragma("unroll") for (int k = 0; k < 8; ++k)                          \
            w1s[m][k] = W1[m * 64 + j * 8 + k];                                \
    float b1r0 = b1[0], b1r1 = b1[1], b1r2 = b1[2], b1r3 = b1[3];              \
    float w2s0 = W2[j*4+0], w2s1 = W2[j*4+1], w2s2 = W2[j*4+2], w2s3 = W2[j*4+3]; \
    float b2r = b2[j];                                                         \
    float wI[8], wF[8], wG[8], wO[8], uI[8], uF[8], uG[8], uO[8];              \
    _Pragma("unroll") for (int k = 0; k < 8; ++k) {                            \
        wI[k] = Wih[j * 8 + k];        uI[k] = Whh[j * 8 + k];                 \
        wF[k] = Wih[(8 + j) * 8 + k];  uF[k] = Whh[(8 + j) * 8 + k];           \
        wG[k] = Wih[(16 + j) * 8 + k]; uG[k] = Whh[(16 + j) * 8 + k];          \
        wO[k] = Wih[(24 + j) * 8 + k]; uO[k] = Whh[(24 + j) * 8 + k];          \
    }                                                                          \
    float bI = bih[j] + bhh[j],      bF = bih[8 + j] + bhh[8 + j];             \
    float bG = bih[16 + j] + bhh[16 + j], bO = bih[24 + j] + bhh[24 + j];      \
    float hw0[8], hw1[8], hw2[8];                                              \
    float hb0 = ba[j], hb1 = ba[8 + j], hb2 = 0.f;                             \
    _Pragma("unroll") for (int k = 0; k < 8; ++k) {                            \
        hw0[k] = Wa[j * 8 + k]; hw1[k] = Wa[(8 + j) * 8 + k]; hw2[k] = 0.f;    \
    }                                                                          \
    if (j < 2) {                                                               \
        _Pragma("unroll") for (int k = 0; k < 8; ++k) hw2[k] = Wa[(16+j)*8+k]; \
        hb2 = ba[16 + j];                                                      \
    } else if (j == 2) {                                                       \
        _Pragma("unroll") for (int k = 0; k < 8; ++k) hw2[k] = Wv[k];          \
        hb2 = bv[0];                                                           \
    }

#define CORE_S(DONEE, SA, SV)                                                  \
        float p0 = SA.x * w1s[0][0], p1 = SA.x * w1s[1][0];                    \
        float p2 = SA.x * w1s[2][0], p3 = SA.x * w1s[3][0];                    \
        p0 = fmaf(SA.y, w1s[0][1], p0); p1 = fmaf(SA.y, w1s[1][1], p1);        \
        p2 = fmaf(SA.y, w1s[2][1], p2); p3 = fmaf(SA.y, w1s[3][1], p3);        \
        p0 = fmaf(SA.z, w1s[0][2], p0); p1 = fmaf(SA.z, w1s[1][2], p1);        \
        p2 = fmaf(SA.z, w1s[2][2], p2); p3 = fmaf(SA.z, w1s[3][2], p3);        \
        p0 = fmaf(SA.w, w1s[0][3], p0); p1 = fmaf(SA.w, w1s[1][3], p1);        \
        p2 = fmaf(SA.w, w1s[2][3], p2); p3 = fmaf(SA.w, w1s[3][3], p3);        \
        p0 = fmaf(SV.x, w1s[0][4], p0); p1 = fmaf(SV.x, w1s[1][4], p1);        \
        p2 = fmaf(SV.x, w1s[2][4], p2); p3 = fmaf(SV.x, w1s[3][4], p3);        \
        p0 = fmaf(SV.y, w1s[0][5], p0); p1 = fmaf(SV.y, w1s[1][5], p1);        \
        p2 = fmaf(SV.y, w1s[2][5], p2); p3 = fmaf(SV.y, w1s[3][5], p3);        \
        p0 = fmaf(SV.z, w1s[0][6], p0); p1 = fmaf(SV.z, w1s[1][6], p1);        \
        p2 = fmaf(SV.z, w1s[2][6], p2); p3 = fmaf(SV.z, w1s[3][6], p3);        \
        p0 = fmaf(SV.w, w1s[0][7], p0); p1 = fmaf(SV.w, w1s[1][7], p1);        \
        p2 = fmaf(SV.w, w1s[2][7], p2); p3 = fmaf(SV.w, w1s[3][7], p3);        \
        p0 += dpp_xor1(p0); p1 += dpp_xor1(p1);                                \
        p2 += dpp_xor1(p2); p3 += dpp_xor1(p3);                                \
        p0 += dpp_xor2(p0); p1 += dpp_xor2(p1);                                \
        p2 += dpp_xor2(p2); p3 += dpp_xor2(p3);                                \
        p0 += __shfl_xor(p0, 4, 64); p1 += __shfl_xor(p1, 4, 64);              \
        p2 += __shfl_xor(p2, 4, 64); p3 += __shfl_xor(p3, 4, 64);              \
        float y0 = fmaxf(p0 + b1r0, 0.f);                                      \
        float y1 = fmaxf(p1 + b1r1, 0.f);                                      \
        float y2 = fmaxf(p2 + b1r2, 0.f);                                      \
        float y3 = fmaxf(p3 + b1r3, 0.f);                                      \
        float xj = fmaf(y3, w2s3, fmaf(y2, w2s2, fmaf(y1, w2s1,                \
                   fmaf(y0, w2s0, b2r))));                                     \
        xj = fmaxf(xj, 0.f);                                                   \
        float x0 = __shfl(xj, gb | 0, 64);                                     \
        float x1 = __shfl(xj, gb | 1, 64);                                     \
        float xx2 = __shfl(xj, gb | 2, 64);                                    \
        float x3 = __shfl(xj, gb | 3, 64);                                     \
        float x4 = __shfl(xj, gb | 4, 64);                                     \
        float x5 = __shfl(xj, gb | 5, 64);                                     \
        float x6 = __shfl(xj, gb | 6, 64);                                     \
        float x7 = __shfl(xj, gb | 7, 64);                                     \
        float gi = bI, gf = bF, gg = bG, go = bO;                              \
        gi = fmaf(x0, wI[0], gi); gi = fmaf(x1, wI[1], gi);                    \
        gi = fmaf(xx2, wI[2], gi); gi = fmaf(x3, wI[3], gi);                   \
        gi = fmaf(x4, wI[4], gi); gi = fmaf(x5, wI[5], gi);                    \
        gi = fmaf(x6, wI[6], gi); gi = fmaf(x7, wI[7], gi);                    \
        gf = fmaf(x0, wF[0], gf); gf = fmaf(x1, wF[1], gf);                    \
        gf = fmaf(xx2, wF[2], gf); gf = fmaf(x3, wF[3], gf);                   \
        gf = fmaf(x4, wF[4], gf); gf = fmaf(x5, wF[5], gf);                    \
        gf = fmaf(x6, wF[6], gf); gf = fmaf(x7, wF[7], gf);                    \
        gg = fmaf(x0, wG[0], gg); gg = fmaf(x1, wG[1], gg);                    \
        gg = fmaf(xx2, wG[2], gg); gg = fmaf(x3, wG[3], gg);                   \
        gg = fmaf(x4, wG[4], gg); gg = fmaf(x5, wG[5], gg);                    \
        gg = fmaf(x6, wG[6], gg); gg = fmaf(x7, wG[7], gg);                    \
        go = fmaf(x0, wO[0], go); go = fmaf(x1, wO[1], go);                    \
        go = fmaf(xx2, wO[2], go); go = fmaf(x3, wO[3], go);                   \
        go = fmaf(x4, wO[4], go); go = fmaf(x5, wO[5], go);                    \
        go = fmaf(x6, wO[6], go); go = fmaf(x7, wO[7], go);                    \
        float dI = h[0] * uI[0], dF = h[0] * uF[0];                            \
        float dG = h[0] * uG[0], dO = h[0] * uO[0];                            \
        dI = fmaf(h[1], uI[1], dI); dF = fmaf(h[1], uF[1], dF);                \
        dG = fmaf(h[1], uG[1], dG); dO = fmaf(h[1], uO[1], dO);                \
        dI = fmaf(h[2], uI[2], dI); dF = fmaf(h[2], uF[2], dF);                \
        dG = fmaf(h[2], uG[2], dG); dO = fmaf(h[2], uO[2], dO);                \
        dI = fmaf(h[3], uI[3], dI); dF = fmaf(h[3], uF[3], dF);                \
        dG = fmaf(h[3], uG[3], dG); dO = fmaf(h[3], uO[3], dO);                \
        dI = fmaf(h[4], uI[4], dI); dF = fmaf(h[4], uF[4], dF);                \
        dG = fmaf(h[4], uG[4], dG); dO = fmaf(h[4], uO[4], dO);                \
        dI = fmaf(h[5], uI[5], dI); dF = fmaf(h[5], uF[5], dF);                \
        dG = fmaf(h[5], uG[5], dG); dO = fmaf(h[5], uO[5], dO);                \
        dI = fmaf(h[6], uI[6], dI); dF = fmaf(h[6], uF[6], dF);                \
        dG = fmaf(h[6], uG[6], dG); dO = fmaf(h[6], uO[6], dO);                \
        dI = fmaf(h[7], uI[7], dI); dF = fmaf(h[7], uF[7], dF);                \
        dG = fmaf(h[7], uG[7], dG); dO = fmaf(h[7], uO[7], dO);                \
        float GI = (DONEE) ? gi : (gi + dI);                                   \
        float GF = (DONEE) ? gf : (gf + dF);                                   \
        float GG = (DONEE) ? gg : (gg + dG);                                   \
        float GO = (DONEE) ? go : (go + dO);                                   \
        float cin = (DONEE) ? 0.f : c;                                         \
        float i_ = SIGM(GI);                                                   \
        float f_ = SIGM(GF);                                                   \
        float g_ = TANH(GG);                                                   \
        float o_ = SIGM(GO);                                                   \
        float c2 = fmaf(f_, cin, i_ * g_);                                     \
        float th = TANH(c2);                                                   \
        float h2 = o_ * th;

#define HEADS                                                                  \
        float o0 = hb0, o1 = hb1, o2 = hb2;                                    \
        o0 = fmaf(h[0], hw0[0], o0); o1 = fmaf(h[0], hw1[0], o1);              \
        o2 = fmaf(h[0], hw2[0], o2);                                           \
        o0 = fmaf(h[1], hw0[1], o0); o1 = fmaf(h[1], hw1[1], o1);              \
        o2 = fmaf(h[1], hw2[1], o2);                                           \
        o0 = fmaf(h[2], hw0[2], o0); o1 = fmaf(h[2], hw1[2], o1);              \
        o2 = fmaf(h[2], hw2[2], o2);                                           \
        o0 = fmaf(h[3], hw0[3], o0); o1 = fmaf(h[3], hw1[3], o1);              \
        o2 = fmaf(h[3], hw2[3], o2);                                           \
        o0 = fmaf(h[4], hw0[4], o0); o1 = fmaf(h[4], hw1[4], o1);              \
        o2 = fmaf(h[4], hw2[4], o2);                                           \
        o0 = fmaf(h[5], hw0[5], o0); o1 = fmaf(h[5], hw1[5], o1);              \
        o2 = fmaf(h[5], hw2[5], o2);                                           \
        o0 = fmaf(h[6], hw0[6], o0); o1 = fmaf(h[6], hw1[6], o1);              \
        o2 = fmaf(h[6], hw2[6], o2);                                           \
        o0 = fmaf(h[7], hw0[7], o0); o1 = fmaf(h[7], hw1[7], o1);              \
        o2 = fmaf(h[7], hw2[7], o2);

#define HSHFL                                                                  \
        h[0] = __shfl(h2, gb | 0, 64); h[1] = __shfl(h2, gb | 1, 64);          \
        h[2] = __shfl(h2, gb | 2, 64); h[3] = __shfl(h2, gb | 3, 64);          \
        h[4] = __shfl(h2, gb | 4, 64); h[5] = __shfl(h2, gb | 5, 64);          \
        h[6] = __shfl(h2, gb | 6, 64); h[7] = __shfl(h2, gb | 7, 64);

// ---------------------------------------------------------------------------
// Pass 1 (R18 body, 4 waves per workgroup): block 256 = 4 independent wave-
// segments; grid NSEG*128. Tests the workgroup-slot occupancy hypothesis.
// ---------------------------------------------------------------------------
__global__ __launch_bounds__(256) void pass1_kernel(
    const float* __restrict__ states, const int* __restrict__ dones,
    const float* __restrict__ hx,
    const float* __restrict__ W1, const float* __restrict__ b1,
    const float* __restrict__ W2, const float* __restrict__ b2,
    const float* __restrict__ Wih, const float* __restrict__ bih,
    const float* __restrict__ Whh, const float* __restrict__ bhh,
    const float* __restrict__ Wa, const float* __restrict__ ba,
    const float* __restrict__ Wv, const float* __restrict__ bv,
    float* __restrict__ out,
    float* __restrict__ carryH, float* __restrict__ carryC,
    int* __restrict__ fdbuf)
{
    int lane = threadIdx.x & 63;
    int wv   = threadIdx.x >> 6;         // wave within block: 0..3
    int col  = lane >> 3;
    int j    = lane & 7;
    int gb   = lane & 56;
    int s    = blockIdx.x >> 7;          // 0..7 (128 blocks per segment)
    int tb   = (blockIdx.x & 127) * 4 + wv;   // 0..511
    int t    = tb * 8 + col;
    int b0   = s * SEGLEN;

    LOAD_WEIGHTS

    float h[8]; float c;
    if (s == 0) {
#pragma unroll
        for (int m = 0; m < 8; ++m) h[m] = hx[t * 8 + m];
        c = hx[T_DIM * 8 + t * 8 + j];
    } else {
#pragma unroll
        for (int m = 0; m < 8; ++m) h[m] = 0.f;
        c = 0.f;
    }

    const float* sbase = states + ((size_t)b0 * T_DIM + t) * 64 + j * 8;
    const int*   dbase = dones + (size_t)b0 * T_DIM + t;
    float* outA = out + ((size_t)b0 * T_DIM + t) * 18;
    float* outV = out + (size_t)18 * B_DIM * T_DIM + (size_t)b0 * T_DIM + t;
    int fd = SEGLEN;

    // 4-deep prefetch (named registers)
    int dn0, dn1, dn2, dn3;
    float4 sa0, sv0, sa1, sv1, sa2, sv2, sa3, sv3;
#define PF(I) \
    dn##I = dbase[(size_t)(I) * T_DIM]; \
    sa##I = *(const float4*)(sbase + (size_t)(I) * BSTRIDE); \
    sv##I = *(const float4*)(sbase + (size_t)(I) * BSTRIDE + 4);
    PF(0) PF(1) PF(2) PF(3)
#undef PF

#define P1STEP(KK, DN, SA, SV)                                                 \
    {                                                                          \
        int done = DN; float4 sa = SA, sv = SV;                                \
        int kp = (KK) + 4; kp = (kp > SEGLEN - 1) ? (SEGLEN - 1) : kp;         \
        DN = dbase[(size_t)kp * T_DIM];                                        \
        SA = *(const float4*)(sbase + (size_t)kp * BSTRIDE);                   \
        SV = *(const float4*)(sbase + (size_t)kp * BSTRIDE + 4);               \
        CORE_S(done, sa, sv)                                                   \
        c = c2;                                                                \
        HSHFL                                                                  \
        fd = (done && fd == SEGLEN) ? (KK) : fd;                               \
        HEADS                                                                  \
        outA[j] = o0; outA[8 + j] = o1;                                        \
        if (j < 2) outA[16 + j] = o2; else if (j == 2) *outV = o2;             \
        outA += (size_t)T_DIM * 18; outV += T_DIM;                             \
    }

    for (int k0 = 0; k0 < SEGLEN; k0 += 4) {
        P1STEP(k0 + 0, dn0, sa0, sv0);
        P1STEP(k0 + 1, dn1, sa1, sv1);
        P1STEP(k0 + 2, dn2, sa2, sv2);
        P1STEP(k0 + 3, dn3, sa3, sv3);
    }
#undef P1STEP

    carryH[((size_t)s * T_DIM + t) * 8 + j] = h[j];
    carryC[((size_t)s * T_DIM + t) * 8 + j] = c;
    if (j == 0) fdbuf[(size_t)s * T_DIM + t] = fd;
}

// ---------------------------------------------------------------------------
// Pass 2 (R18 body, 4 waves per workgroup).
// ---------------------------------------------------------------------------
__global__ __launch_bounds__(256) void pass2_kernel(
    const float* __restrict__ states, const int* __restrict__ dones,
    const float* __restrict__ W1, const float* __restrict__ b1,
    const float* __restrict__ W2, const float* __restrict__ b2,
    const float* __restrict__ Wih, const float* __restrict__ bih,
    const float* __restrict__ Whh, const float* __restrict__ bhh,
    const float* __restrict__ Wa, const float* __restrict__ ba,
    const float* __restrict__ Wv, const float* __restrict__ bv,
    float* __restrict__ out,
    const float* __restrict__ carryH, const float* __restrict__ carryC,
    const int* __restrict__ fdbuf)
{
    int lane = threadIdx.x & 63;
    int wv   = threadIdx.x >> 6;
    int col  = lane >> 3;
    int j    = lane & 7;
    int gb   = lane & 56;
    int s    = 1 + (int)(blockIdx.x >> 7);    // 1..NSEG-1
    int tb   = (blockIdx.x & 127) * 4 + wv;
    int t    = tb * 8 + col;

    LOAD_WEIGHTS

    const float* sb2 = states + (size_t)t * 64 + j * 8;

    float h[8]; float c;
    bool prev_exact = (s == 1) ||
                      (fdbuf[(size_t)(s - 1) * T_DIM + t] < SEGLEN);
    if (__all(prev_exact)) {
#pragma unroll
        for (int m = 0; m < 8; ++m)
            h[m] = carryH[((size_t)(s - 1) * T_DIM + t) * 8 + m];
        c = carryC[((size_t)(s - 1) * T_DIM + t) * 8 + j];
    } else {
#pragma unroll
        for (int m = 0; m < 8; ++m) h[m] = carryH[(size_t)t * 8 + m];
        c = carryC[(size_t)t * 8 + j];
        for (int p = 1; p <= s - 1; ++p) {
            size_t bb = (size_t)p * SEGLEN;
            for (int k = 0; k < SEGLEN; ++k) {
                int done = dones[(bb + k) * T_DIM + t];
                float4 sa = *(const float4*)(sb2 + (bb + k) * BSTRIDE);
                float4 sv = *(const float4*)(sb2 + (bb + k) * BSTRIDE + 4);
                CORE_S(done, sa, sv)
                c = c2;
                HSHFL
            }
            int fdp = fdbuf[(size_t)p * T_DIM + t];
            if (fdp < SEGLEN) {
#pragma unroll
                for (int m = 0; m < 8; ++m)
                    h[m] = carryH[((size_t)p * T_DIM + t) * 8 + m];
                c = carryC[((size_t)p * T_DIM + t) * 8 + j];
            }
        }
    }

    int fd = fdbuf[(size_t)s * T_DIM + t];
    int wmax = fd;
#pragma unroll
    for (int d = 1; d < 64; d <<= 1) {
        int o = __shfl_xor(wmax, d, 64);
        wmax = (o > wmax) ? o : wmax;
    }
    size_t bbase = (size_t)s * SEGLEN;
    float4 csa = *(const float4*)(sb2 + bbase * BSTRIDE);
    float4 csv = *(const float4*)(sb2 + bbase * BSTRIDE + 4);
    for (int k = 0; k < wmax; ++k) {
        bool act = (k < fd);                 // no dones in [0, fd) by def.
        float4 sa = csa, sv = csv;
        int kn = k + 1; kn = (kn > SEGLEN - 1) ? (SEGLEN - 1) : kn;
        csa = *(const float4*)(sb2 + (bbase + kn) * BSTRIDE);
        csv = *(const float4*)(sb2 + (bbase + kn) * BSTRIDE + 4);
        CORE_S(0, sa, sv)
        c = act ? c2 : c;
        float n0 = __shfl(h2, gb | 0, 64), n1 = __shfl(h2, gb | 1, 64);
        float n2 = __shfl(h2, gb | 2, 64), n3 = __shfl(h2, gb | 3, 64);
        float n4 = __shfl(h2, gb | 4, 64), n5 = __shfl(h2, gb | 5, 64);
        float n6 = __shfl(h2, gb | 6, 64), n7 = __shfl(h2, gb | 7, 64);
        h[0] = act ? n0 : h[0]; h[1] = act ? n1 : h[1];
        h[2] = act ? n2 : h[2]; h[3] = act ? n3 : h[3];
        h[4] = act ? n4 : h[4]; h[5] = act ? n5 : h[5];
        h[6] = act ? n6 : h[6]; h[7] = act ? n7 : h[7];
        HEADS
        if (act) {
            float* outA = out + ((bbase + k) * T_DIM + t) * 18;
            outA[j] = o0; outA[8 + j] = o1;
            if (j < 2) outA[16 + j] = o2;
            else if (j == 2)
                out[(size_t)18 * B_DIM * T_DIM + (bbase + k) * T_DIM + t] = o2;
        }
    }
}

// ---------------------------------------------------------------------------
extern "C" void kernel_launch(void* const* d_in, const int* in_sizes, int n_in,
                              void* d_out, int out_size, void* d_ws, size_t ws_size,
                              hipStream_t stream) {
    (void)in_sizes; (void)n_in; (void)out_size; (void)ws_size;
    const float* states = (const float*)d_in[0];
    const int*   dones  = (const int*)d_in[1];
    const float* hx     = (const float*)d_in[2];
    const float* W1     = (const float*)d_in[3];
    const float* b1     = (const float*)d_in[4];
    const float* W2     = (const float*)d_in[5];
    const float* b2     = (const float*)d_in[6];
    const float* Wih    = (const float*)d_in[7];
    const float* bih    = (const float*)d_in[8];
    const float* Whh    = (const float*)d_in[9];
    const float* bhh    = (const float*)d_in[10];
    const float* Wa     = (const float*)d_in[11];
    const float* ba     = (const float*)d_in[12];
    const float* Wv     = (const float*)d_in[13];
    const float* bv     = (const float*)d_in[14];
    float* out = (float*)d_out;

    float* carryH = (float*)d_ws;                               // 1 MiB
    float* carryC = (float*)((char*)d_ws + (1u << 20));         // 1 MiB
    int*   fdbuf  = (int*)((char*)d_ws + (2u << 20));           // 128 KiB

    pass1_kernel<<<NSEG * 128, 256, 0, stream>>>(states, dones, hx, W1, b1, W2, b2,
                                                 Wih, bih, Whh, bhh, Wa, ba, Wv, bv,
                                                 out, carryH, carryC, fdbuf);
    pass2_kernel<<<(NSEG - 1) * 128, 256, 0, stream>>>(states, dones, W1, b1, W2, b2,
                                                       Wih, bih, Whh, bhh, Wa, ba, Wv, bv,
                                                       out, carryH, carryC, fdbuf);
}

// Round 21
// 92.079 us; speedup vs baseline: 3.0874x; 1.0113x over previous
//
#include <hip/hip_runtime.h>

#define T_DIM 4096
#define B_DIM 256
#define NSEG 8
#define SEGLEN 32
#define BSTRIDE ((size_t)T_DIM * 64)   // floats per b-step in states
// N_OBS=64, H=8, N_ACT=18

typedef float v2f __attribute__((ext_vector_type(2)));
__device__ __forceinline__ v2f mk2(float a, float b) { v2f r; r.x = a; r.y = b; return r; }

// fast sigmoid/tanh via v_rcp_f32 (~1 ULP; verified R13)
#define SIGM(X)  __builtin_amdgcn_rcpf(1.f + __expf(-(X)))
#define TANH(X)  fmaf(2.f, __builtin_amdgcn_rcpf(1.f + __expf(-2.f * (X))), -1.f)

// DPP cross-lane on the VALU pipe (no DS): quad_perm xor1 = 0xB1, xor2 = 0x4E.
__device__ __forceinline__ float dpp_xor1(float x) {
    return __int_as_float(__builtin_amdgcn_update_dpp(
        0, __float_as_int(x), 0xB1, 0xF, 0xF, true));
}
__device__ __forceinline__ float dpp_xor2(float x) {
    return __int_as_float(__builtin_amdgcn_update_dpp(
        0, __float_as_int(x), 0x4E, 0xF, 0xF, true));
}

// ws layout: carryH 1 MiB @ 0, carryC 1 MiB @ 1 MiB, fdbuf 128 KiB @ 2 MiB

// ---------------------------------------------------------------------------
// Per-lane weights, PAIR-INTERLEAVED for packed FP32 (v_pk_fma_f32):
// {i,f} and {g,o} gate rows share multiplicands; MLP rows {0,1},{2,3};
// head rows {ja, 8+j}. Lane mapping / shuffles unchanged from R20.
// ---------------------------------------------------------------------------
#define LOAD_WEIGHTS                                                           \
    v2f w1p01[8], w1p23[8];                                                    \
    _Pragma("unroll") for (int k = 0; k < 8; ++k) {                            \
        w1p01[k] = mk2(W1[j * 8 + k],       W1[64 + j * 8 + k]);               \
        w1p23[k] = mk2(W1[128 + j * 8 + k], W1[192 + j * 8 + k]);              \
    }                                                                          \
    float b1r0 = b1[0], b1r1 = b1[1], b1r2 = b1[2], b1r3 = b1[3];              \
    float w2s0 = W2[j*4+0], w2s1 = W2[j*4+1], w2s2 = W2[j*4+2], w2s3 = W2[j*4+3]; \
    float b2r = b2[j];                                                         \
    v2f wIF[8], wGO[8], uIF[8], uGO[8];                                        \
    _Pragma("unroll") for (int k = 0; k < 8; ++k) {                            \
        wIF[k] = mk2(Wih[j * 8 + k],        Wih[(8 + j) * 8 + k]);             \
        wGO[k] = mk2(Wih[(16 + j) * 8 + k], Wih[(24 + j) * 8 + k]);            \
        uIF[k] = mk2(Whh[j * 8 + k],        Whh[(8 + j) * 8 + k]);             \
        uGO[k] = mk2(Whh[(16 + j) * 8 + k], Whh[(24 + j) * 8 + k]);            \
    }                                                                          \
    v2f bIF = mk2(bih[j] + bhh[j],           bih[8 + j] + bhh[8 + j]);         \
    v2f bGO = mk2(bih[16 + j] + bhh[16 + j], bih[24 + j] + bhh[24 + j]);       \
    v2f hw01[8]; float hw2[8];                                                 \
    v2f hb01 = mk2(ba[j], ba[8 + j]); float hb2 = 0.f;                         \
    _Pragma("unroll") for (int k = 0; k < 8; ++k) {                            \
        hw01[k] = mk2(Wa[j * 8 + k], Wa[(8 + j) * 8 + k]); hw2[k] = 0.f;       \
    }                                                                          \
    if (j < 2) {                                                               \
        _Pragma("unroll") for (int k = 0; k < 8; ++k) hw2[k] = Wa[(16+j)*8+k]; \
        hb2 = ba[16 + j];                                                      \
    } else if (j == 2) {                                                       \
        _Pragma("unroll") for (int k = 0; k < 8; ++k) hw2[k] = Wv[k];          \
        hb2 = bv[0];                                                           \
    }

// ---------------------------------------------------------------------------
// Fused CORE (R20 structure): MLP partial pairs, gate pairs {i,f}/{g,o}, all
// as packed float2 chains (scalar multiplicand splat -> v_pk_fma_f32).
// Butterfly/broadcast/activations unchanged.
// ---------------------------------------------------------------------------
#define CORE_S(DONEE, SA, SV)                                                  \
        v2f p01 = SA.x * w1p01[0], p23 = SA.x * w1p23[0];                      \
        p01 += SA.y * w1p01[1]; p23 += SA.y * w1p23[1];                        \
        p01 += SA.z * w1p01[2]; p23 += SA.z * w1p23[2];                        \
        p01 += SA.w * w1p01[3]; p23 += SA.w * w1p23[3];                        \
        p01 += SV.x * w1p01[4]; p23 += SV.x * w1p23[4];                        \
        p01 += SV.y * w1p01[5]; p23 += SV.y * w1p23[5];                        \
        p01 += SV.z * w1p01[6]; p23 += SV.z * w1p23[6];                        \
        p01 += SV.w * w1p01[7]; p23 += SV.w * w1p23[7];                        \
        float p0 = p01.x, p1 = p01.y, p2 = p23.x, p3 = p23.y;                  \
        p0 += dpp_xor1(p0); p1 += dpp_xor1(p1);                                \
        p2 += dpp_xor1(p2); p3 += dpp_xor1(p3);                                \
        p0 += dpp_xor2(p0); p1 += dpp_xor2(p1);                                \
        p2 += dpp_xor2(p2); p3 += dpp_xor2(p3);                                \
        p0 += __shfl_xor(p0, 4, 64); p1 += __shfl_xor(p1, 4, 64);              \
        p2 += __shfl_xor(p2, 4, 64); p3 += __shfl_xor(p3, 4, 64);              \
        float y0 = fmaxf(p0 + b1r0, 0.f);                                      \
        float y1 = fmaxf(p1 + b1r1, 0.f);                                      \
        float y2 = fmaxf(p2 + b1r2, 0.f);                                      \
        float y3 = fmaxf(p3 + b1r3, 0.f);                                      \
        float xj = fmaf(y3, w2s3, fmaf(y2, w2s2, fmaf(y1, w2s1,                \
                   fmaf(y0, w2s0, b2r))));                                     \
        xj = fmaxf(xj, 0.f);                                                   \
        float x0 = __shfl(xj, gb | 0, 64);                                     \
        float x1 = __shfl(xj, gb | 1, 64);                                     \
        float xx2 = __shfl(xj, gb | 2, 64);                                    \
        float x3 = __shfl(xj, gb | 3, 64);                                     \
        float x4 = __shfl(xj, gb | 4, 64);                                     \
        float x5 = __shfl(xj, gb | 5, 64);                                     \
        float x6 = __shfl(xj, gb | 6, 64);                                     \
        float x7 = __shfl(xj, gb | 7, 64);                                     \
        v2f gIF = bIF, gGO = bGO;                                              \
        gIF += x0 * wIF[0]; gGO += x0 * wGO[0];                                \
        gIF += x1 * wIF[1]; gGO += x1 * wGO[1];                                \
        gIF += xx2 * wIF[2]; gGO += xx2 * wGO[2];                              \
        gIF += x3 * wIF[3]; gGO += x3 * wGO[3];                                \
        gIF += x4 * wIF[4]; gGO += x4 * wGO[4];                                \
        gIF += x5 * wIF[5]; gGO += x5 * wGO[5];                                \
        gIF += x6 * wIF[6]; gGO += x6 * wGO[6];                                \
        gIF += x7 * wIF[7]; gGO += x7 * wGO[7];                                \
        v2f dIF = h[0] * uIF[0], dGO = h[0] * uGO[0];                          \
        dIF += h[1] * uIF[1]; dGO += h[1] * uGO[1];                            \
        dIF += h[2] * uIF[2]; dGO += h[2] * uGO[2];                            \
        dIF += h[3] * uIF[3]; dGO += h[3] * uGO[3];                            \
        dIF += h[4] * uIF[4]; dGO += h[4] * uGO[4];                            \
        dIF += h[5] * uIF[5]; dGO += h[5] * uGO[5];                            \
        dIF += h[6] * uIF[6]; dGO += h[6] * uGO[6];                            \
        dIF += h[7] * uIF[7]; dGO += h[7] * uGO[7];                            \
        float GI = (DONEE) ? gIF.x : (gIF.x + dIF.x);                          \
        float GF = (DONEE) ? gIF.y : (gIF.y + dIF.y);                          \
        float GG = (DONEE) ? gGO.x : (gGO.x + dGO.x);                          \
        float GO = (DONEE) ? gGO.y : (gGO.y + dGO.y);                          \
        float cin = (DONEE) ? 0.f : c;                                         \
        float i_ = SIGM(GI);                                                   \
        float f_ = SIGM(GF);                                                   \
        float g_ = TANH(GG);                                                   \
        float o_ = SIGM(GO);                                                   \
        float c2 = fmaf(f_, cin, i_ * g_);                                     \
        float th = TANH(c2);                                                   \
        float h2 = o_ * th;

#define HEADS                                                                  \
        v2f o01 = hb01;                                                        \
        o01 += h[0] * hw01[0]; o01 += h[1] * hw01[1];                          \
        o01 += h[2] * hw01[2]; o01 += h[3] * hw01[3];                          \
        o01 += h[4] * hw01[4]; o01 += h[5] * hw01[5];                          \
        o01 += h[6] * hw01[6]; o01 += h[7] * hw01[7];                          \
        float o2 = hb2;                                                        \
        o2 = fmaf(h[0], hw2[0], o2); o2 = fmaf(h[1], hw2[1], o2);              \
        o2 = fmaf(h[2], hw2[2], o2); o2 = fmaf(h[3], hw2[3], o2);              \
        o2 = fmaf(h[4], hw2[4], o2); o2 = fmaf(h[5], hw2[5], o2);              \
        o2 = fmaf(h[6], hw2[6], o2); o2 = fmaf(h[7], hw2[7], o2);              \
        float o0 = o01.x, o1 = o01.y;

#define HSHFL                                                                  \
        h[0] = __shfl(h2, gb | 0, 64); h[1] = __shfl(h2, gb | 1, 64);          \
        h[2] = __shfl(h2, gb | 2, 64); h[3] = __shfl(h2, gb | 3, 64);          \
        h[4] = __shfl(h2, gb | 4, 64); h[5] = __shfl(h2, gb | 5, 64);          \
        h[6] = __shfl(h2, gb | 6, 64); h[7] = __shfl(h2, gb | 7, 64);

// ---------------------------------------------------------------------------
// Pass 1 (R20 structure: 4 waves/workgroup, 4-deep prefetch).
// ---------------------------------------------------------------------------
__global__ __launch_bounds__(256) void pass1_kernel(
    const float* __restrict__ states, const int* __restrict__ dones,
    const float* __restrict__ hx,
    const float* __restrict__ W1, const float* __restrict__ b1,
    const float* __restrict__ W2, const float* __restrict__ b2,
    const float* __restrict__ Wih, const float* __restrict__ bih,
    const float* __restrict__ Whh, const float* __restrict__ bhh,
    const float* __restrict__ Wa, const float* __restrict__ ba,
    const float* __restrict__ Wv, const float* __restrict__ bv,
    float* __restrict__ out,
    float* __restrict__ carryH, float* __restrict__ carryC,
    int* __restrict__ fdbuf)
{
    int lane = threadIdx.x & 63;
    int wv   = threadIdx.x >> 6;         // wave within block: 0..3
    int col  = lane >> 3;
    int j    = lane & 7;
    int gb   = lane & 56;
    int s    = blockIdx.x >> 7;          // 0..7 (128 blocks per segment)
    int tb   = (blockIdx.x & 127) * 4 + wv;   // 0..511
    int t    = tb * 8 + col;
    int b0   = s * SEGLEN;

    LOAD_WEIGHTS

    float h[8]; float c;
    if (s == 0) {
#pragma unroll
        for (int m = 0; m < 8; ++m) h[m] = hx[t * 8 + m];
        c = hx[T_DIM * 8 + t * 8 + j];
    } else {
#pragma unroll
        for (int m = 0; m < 8; ++m) h[m] = 0.f;
        c = 0.f;
    }

    const float* sbase = states + ((size_t)b0 * T_DIM + t) * 64 + j * 8;
    const int*   dbase = dones + (size_t)b0 * T_DIM + t;
    float* outA = out + ((size_t)b0 * T_DIM + t) * 18;
    float* outV = out + (size_t)18 * B_DIM * T_DIM + (size_t)b0 * T_DIM + t;
    int fd = SEGLEN;

    // 4-deep prefetch (named registers)
    int dn0, dn1, dn2, dn3;
    float4 sa0, sv0, sa1, sv1, sa2, sv2, sa3, sv3;
#define PF(I) \
    dn##I = dbase[(size_t)(I) * T_DIM]; \
    sa##I = *(const float4*)(sbase + (size_t)(I) * BSTRIDE); \
    sv##I = *(const float4*)(sbase + (size_t)(I) * BSTRIDE + 4);
    PF(0) PF(1) PF(2) PF(3)
#undef PF

#define P1STEP(KK, DN, SA, SV)                                                 \
    {                                                                          \
        int done = DN; float4 sa = SA, sv = SV;                                \
        int kp = (KK) + 4; kp = (kp > SEGLEN - 1) ? (SEGLEN - 1) : kp;         \
        DN = dbase[(size_t)kp * T_DIM];                                        \
        SA = *(const float4*)(sbase + (size_t)kp * BSTRIDE);                   \
        SV = *(const float4*)(sbase + (size_t)kp * BSTRIDE + 4);               \
        CORE_S(done, sa, sv)                                                   \
        c = c2;                                                                \
        HSHFL                                                                  \
        fd = (done && fd == SEGLEN) ? (KK) : fd;                               \
        HEADS                                                                  \
        outA[j] = o0; outA[8 + j] = o1;                                        \
        if (j < 2) outA[16 + j] = o2; else if (j == 2) *outV = o2;             \
        outA += (size_t)T_DIM * 18; outV += T_DIM;                             \
    }

    for (int k0 = 0; k0 < SEGLEN; k0 += 4) {
        P1STEP(k0 + 0, dn0, sa0, sv0);
        P1STEP(k0 + 1, dn1, sa1, sv1);
        P1STEP(k0 + 2, dn2, sa2, sv2);
        P1STEP(k0 + 3, dn3, sa3, sv3);
    }
#undef P1STEP

    carryH[((size_t)s * T_DIM + t) * 8 + j] = h[j];
    carryC[((size_t)s * T_DIM + t) * 8 + j] = c;
    if (j == 0) fdbuf[(size_t)s * T_DIM + t] = fd;
}

// ---------------------------------------------------------------------------
// Pass 2 (R20 structure, packed CORE).
// ---------------------------------------------------------------------------
__global__ __launch_bounds__(256) void pass2_kernel(
    const float* __restrict__ states, const int* __restrict__ dones,
    const float* __restrict__ W1, const float* __restrict__ b1,
    const float* __restrict__ W2, const float* __restrict__ b2,
    const float* __restrict__ Wih, const float* __restrict__ bih,
    const float* __restrict__ Whh, const float* __restrict__ bhh,
    const float* __restrict__ Wa, const float* __restrict__ ba,
    const float* __restrict__ Wv, const float* __restrict__ bv,
    float* __restrict__ out,
    const float* __restrict__ carryH, const float* __restrict__ carryC,
    const int* __restrict__ fdbuf)
{
    int lane = threadIdx.x & 63;
    int wv   = threadIdx.x >> 6;
    int col  = lane >> 3;
    int j    = lane & 7;
    int gb   = lane & 56;
    int s    = 1 + (int)(blockIdx.x >> 7);    // 1..NSEG-1
    int tb   = (blockIdx.x & 127) * 4 + wv;
    int t    = tb * 8 + col;

    LOAD_WEIGHTS

    const float* sb2 = states + (size_t)t * 64 + j * 8;

    float h[8]; float c;
    bool prev_exact = (s == 1) ||
                      (fdbuf[(size_t)(s - 1) * T_DIM + t] < SEGLEN);
    if (__all(prev_exact)) {
#pragma unroll
        for (int m = 0; m < 8; ++m)
            h[m] = carryH[((size_t)(s - 1) * T_DIM + t) * 8 + m];
        c = carryC[((size_t)(s - 1) * T_DIM + t) * 8 + j];
    } else {
#pragma unroll
        for (int m = 0; m < 8; ++m) h[m] = carryH[(size_t)t * 8 + m];
        c = carryC[(size_t)t * 8 + j];
        for (int p = 1; p <= s - 1; ++p) {
            size_t bb = (size_t)p * SEGLEN;
            for (int k = 0; k < SEGLEN; ++k) {
                int done = dones[(bb + k) * T_DIM + t];
                float4 sa = *(const float4*)(sb2 + (bb + k) * BSTRIDE);
                float4 sv = *(const float4*)(sb2 + (bb + k) * BSTRIDE + 4);
                CORE_S(done, sa, sv)
                c = c2;
                HSHFL
            }
            int fdp = fdbuf[(size_t)p * T_DIM + t];
            if (fdp < SEGLEN) {
#pragma unroll
                for (int m = 0; m < 8; ++m)
                    h[m] = carryH[((size_t)p * T_DIM + t) * 8 + m];
                c = carryC[((size_t)p * T_DIM + t) * 8 + j];
            }
        }
    }

    int fd = fdbuf[(size_t)s * T_DIM + t];
    int wmax = fd;
#pragma unroll
    for (int d = 1; d < 64; d <<= 1) {
        int o = __shfl_xor(wmax, d, 64);
        wmax = (o > wmax) ? o : wmax;
    }
    size_t bbase = (size_t)s * SEGLEN;
    float4 csa = *(const float4*)(sb2 + bbase * BSTRIDE);
    float4 csv = *(const float4*)(sb2 + bbase * BSTRIDE + 4);
    for (int k = 0; k < wmax; ++k) {
        bool act = (k < fd);                 // no dones in [0, fd) by def.
        float4 sa = csa, sv = csv;
        int kn = k + 1; kn = (kn > SEGLEN - 1) ? (SEGLEN - 1) : kn;
        csa = *(const float4*)(sb2 + (bbase + kn) * BSTRIDE);
        csv = *(const float4*)(sb2 + (bbase + kn) * BSTRIDE + 4);
        CORE_S(0, sa, sv)
        c = act ? c2 : c;
        float n0 = __shfl(h2, gb | 0, 64), n1 = __shfl(h2, gb | 1, 64);
        float n2 = __shfl(h2, gb | 2, 64), n3 = __shfl(h2, gb | 3, 64);
        float n4 = __shfl(h2, gb | 4, 64), n5 = __shfl(h2, gb | 5, 64);
        float n6 = __shfl(h2, gb | 6, 64), n7 = __shfl(h2, gb | 7, 64);
        h[0] = act ? n0 : h[0]; h[1] = act ? n1 : h[1];
        h[2] = act ? n2 : h[2]; h[3] = act ? n3 : h[3];
        h[4] = act ? n4 : h[4]; h[5] = act ? n5 : h[5];
        h[6] = act ? n6 : h[6]; h[7] = act ? n7 : h[7];
        HEADS
        if (act) {
            float* outA = out + ((bbase + k) * T_DIM + t) * 18;
            outA[j] = o0; outA[8 + j] = o1;
            if (j < 2) outA[16 + j] = o2;
            else if (j == 2)
                out[(size_t)18 * B_DIM * T_DIM + (bbase + k) * T_DIM + t] = o2;
        }
    }
}

// ---------------------------------------------------------------------------
extern "C" void kernel_launch(void* const* d_in, const int* in_sizes, int n_in,
                              void* d_out, int out_size, void* d_ws, size_t ws_size,
                              hipStream_t stream) {
    (void)in_sizes; (void)n_in; (void)out_size; (void)ws_size;
    const float* states = (const float*)d_in[0];
    const int*   dones  = (const int*)d_in[1];
    const float* hx     = (const float*)d_in[2];
    const float* W1     = (const float*)d_in[3];
    const float* b1     = (const float*)d_in[4];
    const float* W2     = (const float*)d_in[5];
    const float* b2     = (const float*)d_in[6];
    const float* Wih    = (const float*)d_in[7];
    const float* bih    = (const float*)d_in[8];
    const float* Whh    = (const float*)d_in[9];
    const float* bhh    = (const float*)d_in[10];
    const float* Wa     = (const float*)d_in[11];
    const float* ba     = (const float*)d_in[12];
    const float* Wv     = (const float*)d_in[13];
    const float* bv     = (const float*)d_in[14];
    float* out = (float*)d_out;

    float* carryH = (float*)d_ws;                               // 1 MiB
    float* carryC = (float*)((char*)d_ws + (1u << 20));         // 1 MiB
    int*   fdbuf  = (int*)((char*)d_ws + (2u << 20));           // 128 KiB

    pass1_kernel<<<NSEG * 128, 256, 0, stream>>>(states, dones, hx, W1, b1, W2, b2,
                                                 Wih, bih, Whh, bhh, Wa, ba, Wv, bv,
                                                 out, carryH, carryC, fdbuf);
    pass2_kernel<<<(NSEG - 1) * 128, 256, 0, stream>>>(states, dones, W1, b1, W2, b2,
                                                       Wih, bih, Whh, bhh, Wa, ba, Wv, bv,
                                                       out, carryH, carryC, fdbuf);
}